// Round 1
// baseline (427.133 us; speedup 1.0000x reference)
//
#include <hip/hip_runtime.h>
#include <math.h>

// Problem constants (from reference setup_inputs)
#define BB 8
#define HH 16
#define LQ 128
#define LC 4096
#define DD 1024
#define ROWS (HH * LQ)            // 2048 rows to reduce per (b, lc)
#define R_SLABS 32
#define ROWS_PER_SLAB (ROWS / R_SLABS)  // 64
#define COL_TILES 4               // 1024 cols per tile (256 threads x float4)
#define K1_BLOCKS (BB * COL_TILES * R_SLABS)   // 1024
#define QV_BLOCKS ((BB * DD) / 256)            // 32
#define KTOP 5
#define EPSF 1e-8f

// ---------------------------------------------------------------------------
// KA: fused K1 + qv.
//  blocks [0, 1024): partial column sums of cross_attn [B][H][Lq][Lc] over
//    (H,Lq) — body identical to previous K1 (proven coalesced float4 path,
//    deterministic, no atomics).
//  blocks [1024, 1056): q_vec mean over Lq — body identical to previous
//    K23 else-branch.
//  Also zeroes *out (stream order puts this before KB's atomicAdd).
// ---------------------------------------------------------------------------
__global__ __launch_bounds__(256) void kA_partials_qv(
    const float* __restrict__ attn, const float* __restrict__ q,
    float* __restrict__ partials, float* __restrict__ qv,
    float* __restrict__ out) {
    if (blockIdx.x == 0 && threadIdx.x == 0) *out = 0.0f;

    int blk = blockIdx.x;
    if (blk < K1_BLOCKS) {
        int r = blk % R_SLABS;
        int t = blk / R_SLABS;
        int ct = t % COL_TILES;
        int b = t / COL_TILES;
        int col = ct * 1024 + threadIdx.x * 4;

        const float4* src = (const float4*)(attn + (size_t)b * ROWS * LC
                                                 + (size_t)r * ROWS_PER_SLAB * LC + col);
        float4 acc = make_float4(0.f, 0.f, 0.f, 0.f);
#pragma unroll 8
        for (int m = 0; m < ROWS_PER_SLAB; ++m) {
            float4 v = src[(size_t)m * (LC / 4)];
            acc.x += v.x; acc.y += v.y; acc.z += v.z; acc.w += v.w;
        }
        float4* dst = (float4*)(partials + (size_t)r * BB * LC + (size_t)b * LC + col);
        *dst = acc;
    } else {
        int g = (blk - K1_BLOCKS) * 256 + threadIdx.x;  // [0, B*D)
        int b = g / DD;
        int d = g % DD;
        const float* p = q + (size_t)b * LQ * DD + d;
        float s = 0.f;
#pragma unroll 8
        for (int row = 0; row < LQ; ++row)
            s += p[(size_t)row * DD];
        qv[g] = s * (1.0f / LQ);
    }
}

// ---------------------------------------------------------------------------
// KB: per-batch finalize, fused with the avg reduction.
// grid = B blocks of 1024 threads (16 waves).
//  Phase A: avg[b][c] = sum_r partials[r][b][c], held in registers
//           (4 vals/thread, col = tid*4 + j; float4 loads, fully coalesced).
//           Column sum is ranking-invariant vs the reference's mean.
//  Phase B: top-5 via 5 rounds of shuffle+LDS argmax (low-index tie-break,
//           matching jax.lax.top_k).
//  Phase C: cosine — EXECUTED ONLY BY tid<256 with code and reduction order
//           byte-identical to the previous K4, preserving exact output.
//  atomicAdd mean(1-sim)/(B*K) into *out (out zeroed by KA).
// ---------------------------------------------------------------------------
__global__ __launch_bounds__(1024) void kB_topk_finalize(
    const float* __restrict__ partials, const float* __restrict__ qv,
    const float* __restrict__ ctx, float* __restrict__ out) {
    __shared__ float swv[16];
    __shared__ int   swi[16];
    __shared__ int   s_win;
    __shared__ int   s_top[KTOP];
    __shared__ float sred[4][11];

    int b = blockIdx.x;
    int tid = threadIdx.x;
    int lane = tid & 63;
    int wave = tid >> 6;

    // ---- Phase A: reduce partials into registers; col = tid*4 + j ----
    float v[4] = {0.f, 0.f, 0.f, 0.f};
    const float* pb = partials + (size_t)b * LC + (size_t)tid * 4;
#pragma unroll
    for (int r = 0; r < R_SLABS; ++r) {
        float4 p = *(const float4*)(pb + (size_t)r * BB * LC);
        v[0] += p.x; v[1] += p.y; v[2] += p.z; v[3] += p.w;
    }

    // ---- Phase B: top-5, 5 rounds of block argmax ----
    for (int kk = 0; kk < KTOP; ++kk) {
        float bv = v[0];
        int bj = 0;
#pragma unroll
        for (int j = 1; j < 4; ++j)
            if (v[j] > bv) { bv = v[j]; bj = j; }   // strict > prefers lower col
        int bc = tid * 4 + bj;

        for (int off = 32; off > 0; off >>= 1) {
            float ov = __shfl_down(bv, off);
            int   oc = __shfl_down(bc, off);
            if (ov > bv || (ov == bv && oc < bc)) { bv = ov; bc = oc; }
        }
        if (lane == 0) { swv[wave] = bv; swi[wave] = bc; }
        __syncthreads();
        if (tid == 0) {
            float fv = swv[0]; int fc = swi[0];
#pragma unroll
            for (int w = 1; w < 16; ++w)
                if (swv[w] > fv || (swv[w] == fv && swi[w] < fc)) { fv = swv[w]; fc = swi[w]; }
            s_top[kk] = fc;
            s_win = fc;
        }
        __syncthreads();
        int wc = s_win;
        if ((wc >> 2) == tid) v[wc & 3] = -3.0e38f;  // mask winner in owner's reg
        // no barrier needed: next round's swv write is already ordered after
        // tid0's swv read by the sync above
    }

    // ---- Phase C: cosine (tid<256 only; identical arithmetic to old K4) ----
    if (tid < 256) {
        const float4 q4 = *((const float4*)(qv + (size_t)b * DD + tid * 4));
        float acc[11];
        acc[10] = q4.x * q4.x + q4.y * q4.y + q4.z * q4.z + q4.w * q4.w;
#pragma unroll
        for (int kk = 0; kk < KTOP; ++kk) {
            const float4 c4 = *((const float4*)(ctx + (size_t)b * LC * DD
                                                + (size_t)s_top[kk] * DD + tid * 4));
            acc[kk]     = q4.x * c4.x + q4.y * c4.y + q4.z * c4.z + q4.w * c4.w;
            acc[5 + kk] = c4.x * c4.x + c4.y * c4.y + c4.z * c4.z + c4.w * c4.w;
        }
        for (int off = 32; off > 0; off >>= 1) {
#pragma unroll
            for (int i = 0; i < 11; ++i)
                acc[i] += __shfl_down(acc[i], off);
        }
        if (lane == 0) {
#pragma unroll
            for (int i = 0; i < 11; ++i) sred[wave][i] = acc[i];
        }
    }
    __syncthreads();
    if (tid == 0) {
        float t[11];
#pragma unroll
        for (int i = 0; i < 11; ++i)
            t[i] = sred[0][i] + sred[1][i] + sred[2][i] + sred[3][i];
        float qn = fmaxf(sqrtf(t[10]), EPSF);
        float loss = 0.f;
#pragma unroll
        for (int kk = 0; kk < KTOP; ++kk) {
            float cn = fmaxf(sqrtf(t[5 + kk]), EPSF);
            loss += 1.0f - t[kk] / (qn * cn);
        }
        atomicAdd(out, loss * (1.0f / (BB * KTOP)));
    }
}

extern "C" void kernel_launch(void* const* d_in, const int* in_sizes, int n_in,
                              void* d_out, int out_size, void* d_ws, size_t ws_size,
                              hipStream_t stream) {
    const float* q    = (const float*)d_in[0];  // question_emb   [8,128,1024]
    const float* ctx  = (const float*)d_in[1];  // context_emb    [8,4096,1024]
    const float* attn = (const float*)d_in[2];  // cross_attn     [8,16,128,4096]
    float* out = (float*)d_out;

    // ws layout (floats):
    //   partials: R_SLABS*B*LC = 1,048,576  (4 MB)
    //   qv:       B*D          =     8,192  (32 KB)
    float* partials = (float*)d_ws;
    float* qv = partials + (size_t)R_SLABS * BB * LC;

    kA_partials_qv<<<K1_BLOCKS + QV_BLOCKS, 256, 0, stream>>>(attn, q, partials, qv, out);
    kB_topk_finalize<<<BB, 1024, 0, stream>>>(partials, qv, ctx, out);
}

// Round 2
// 416.602 us; speedup vs baseline: 1.0253x; 1.0253x over previous
//
#include <hip/hip_runtime.h>
#include <math.h>

// Problem constants (from reference setup_inputs)
#define BB 8
#define HH 16
#define LQ 128
#define LC 4096
#define DD 1024
#define ROWS (HH * LQ)            // 2048 rows to reduce per (b, lc)
#define R_SLABS 32
#define ROWS_PER_SLAB (ROWS / R_SLABS)  // 64
#define COL_TILES 4               // 1024 cols per tile (256 threads x float4)
#define K1_BLOCKS (BB * COL_TILES * R_SLABS)   // 1024
#define QV_BLOCKS ((BB * DD) / 256)            // 32
#define KTOP 5
#define EPSF 1e-8f

// ---------------------------------------------------------------------------
// KA: fused attn partials + qv mean.
//  blocks [0, 32): q_vec mean over Lq (placed FIRST so this latency-bound
//    tail overlaps the k1 stream instead of trailing it on 32 CUs).
//  blocks [32, 32+1024): partial column sums of cross_attn [B][H][Lq][Lc]
//    over (H,Lq) — proven coalesced float4 path, deterministic, no atomics.
//    unroll 16 (was 8): more outstanding loads per wave.
//  Also zeroes *out (stream order puts this before K4's atomicAdd).
// ---------------------------------------------------------------------------
__global__ __launch_bounds__(256) void kA_partials_qv(
    const float* __restrict__ attn, const float* __restrict__ q,
    float* __restrict__ partials, float* __restrict__ qv,
    float* __restrict__ out) {
    if (blockIdx.x == 0 && threadIdx.x == 0) *out = 0.0f;

    int blk = blockIdx.x;
    if (blk >= QV_BLOCKS) {
        int kblk = blk - QV_BLOCKS;
        int r = kblk % R_SLABS;
        int t = kblk / R_SLABS;
        int ct = t % COL_TILES;
        int b = t / COL_TILES;
        int col = ct * 1024 + threadIdx.x * 4;

        const float4* src = (const float4*)(attn + (size_t)b * ROWS * LC
                                                 + (size_t)r * ROWS_PER_SLAB * LC + col);
        float4 acc = make_float4(0.f, 0.f, 0.f, 0.f);
#pragma unroll 16
        for (int m = 0; m < ROWS_PER_SLAB; ++m) {
            float4 v = src[(size_t)m * (LC / 4)];
            acc.x += v.x; acc.y += v.y; acc.z += v.z; acc.w += v.w;
        }
        float4* dst = (float4*)(partials + (size_t)r * BB * LC + (size_t)b * LC + col);
        *dst = acc;
    } else {
        int g = blk * 256 + threadIdx.x;  // [0, B*D)
        int b = g / DD;
        int d = g % DD;
        const float* p = q + (size_t)b * LQ * DD + d;
        float s = 0.f;
#pragma unroll 8
        for (int row = 0; row < LQ; ++row)
            s += p[(size_t)row * DD];
        qv[g] = s * (1.0f / LQ);
    }
}

// ---------------------------------------------------------------------------
// K2: wide column-sum of partials -> avg. 128 blocks (128 CUs — this is the
// deconfounding fix: round-1 did this read with 8 blocks and lost ~10-20 µs
// to per-CU latency limits). Column SUM — ranking-invariant vs the
// reference's mean.
// ---------------------------------------------------------------------------
__global__ __launch_bounds__(256) void k2_avg(
    const float* __restrict__ partials, float* __restrict__ avg) {
    int g = blockIdx.x * 256 + threadIdx.x;   // g in [0, B*LC)
    float s = 0.f;
#pragma unroll
    for (int r = 0; r < R_SLABS; ++r)
        s += partials[(size_t)r * BB * LC + g];
    avg[g] = s;
}

// ---------------------------------------------------------------------------
// K4: per-batch finalize — byte-identical to the 423.4 µs baseline version
// (preserves absmax=0.0). grid = B blocks of 256 threads.
// ---------------------------------------------------------------------------
__global__ __launch_bounds__(256) void k4_finalize(
    const float* __restrict__ avg, const float* __restrict__ qv,
    const float* __restrict__ ctx, float* __restrict__ out) {
    __shared__ float swv[4];
    __shared__ int   swi[4];
    __shared__ int   s_win;
    __shared__ int   s_top[KTOP];
    __shared__ float sred[4][11];

    int b = blockIdx.x;
    int tid = threadIdx.x;
    int lane = tid & 63;
    int wave = tid >> 6;

    // avg row in registers; col = j*256 + tid
    float v[16];
#pragma unroll
    for (int j = 0; j < 16; ++j)
        v[j] = avg[(size_t)b * LC + j * 256 + tid];

    // ---- top-5: 5 rounds of block argmax via shuffles ----
    for (int kk = 0; kk < KTOP; ++kk) {
        float bv = v[0];
        int bj = 0;
#pragma unroll
        for (int j = 1; j < 16; ++j)
            if (v[j] > bv) { bv = v[j]; bj = j; }   // strict > prefers lower col
        int bc = bj * 256 + tid;

        for (int off = 32; off > 0; off >>= 1) {
            float ov = __shfl_down(bv, off);
            int   oc = __shfl_down(bc, off);
            if (ov > bv || (ov == bv && oc < bc)) { bv = ov; bc = oc; }
        }
        if (lane == 0) { swv[wave] = bv; swi[wave] = bc; }
        __syncthreads();
        if (tid == 0) {
            float fv = swv[0]; int fc = swi[0];
#pragma unroll
            for (int w = 1; w < 4; ++w)
                if (swv[w] > fv || (swv[w] == fv && swi[w] < fc)) { fv = swv[w]; fc = swi[w]; }
            s_top[kk] = fc;
            s_win = fc;
        }
        __syncthreads();
        int wc = s_win;
        if ((wc & 255) == tid) v[wc >> 8] = -3.0e38f;  // mask winner in owner's reg
        // no barrier needed: next round's swv write is already ordered after
        // tid0's swv read by the sync above
    }

    // ---- cosine: batch 11 reductions (5 dots, 5 c-norms, 1 q-norm) ----
    const float4 q4 = *((const float4*)(qv + (size_t)b * DD + tid * 4));
    float acc[11];
    acc[10] = q4.x * q4.x + q4.y * q4.y + q4.z * q4.z + q4.w * q4.w;
#pragma unroll
    for (int kk = 0; kk < KTOP; ++kk) {
        const float4 c4 = *((const float4*)(ctx + (size_t)b * LC * DD
                                            + (size_t)s_top[kk] * DD + tid * 4));
        acc[kk]        = q4.x * c4.x + q4.y * c4.y + q4.z * c4.z + q4.w * c4.w;
        acc[5 + kk]    = c4.x * c4.x + c4.y * c4.y + c4.z * c4.z + c4.w * c4.w;
    }
    for (int off = 32; off > 0; off >>= 1) {
#pragma unroll
        for (int i = 0; i < 11; ++i)
            acc[i] += __shfl_down(acc[i], off);
    }
    if (lane == 0) {
#pragma unroll
        for (int i = 0; i < 11; ++i) sred[wave][i] = acc[i];
    }
    __syncthreads();
    if (tid == 0) {
        float t[11];
#pragma unroll
        for (int i = 0; i < 11; ++i)
            t[i] = sred[0][i] + sred[1][i] + sred[2][i] + sred[3][i];
        float qn = fmaxf(sqrtf(t[10]), EPSF);
        float loss = 0.f;
#pragma unroll
        for (int kk = 0; kk < KTOP; ++kk) {
            float cn = fmaxf(sqrtf(t[5 + kk]), EPSF);
            loss += 1.0f - t[kk] / (qn * cn);
        }
        atomicAdd(out, loss * (1.0f / (BB * KTOP)));
    }
}

extern "C" void kernel_launch(void* const* d_in, const int* in_sizes, int n_in,
                              void* d_out, int out_size, void* d_ws, size_t ws_size,
                              hipStream_t stream) {
    const float* q    = (const float*)d_in[0];  // question_emb   [8,128,1024]
    const float* ctx  = (const float*)d_in[1];  // context_emb    [8,4096,1024]
    const float* attn = (const float*)d_in[2];  // cross_attn     [8,16,128,4096]
    float* out = (float*)d_out;

    // ws layout (floats):
    //   partials: R_SLABS*B*LC = 1,048,576  (4 MB)
    //   avg:      B*LC         =    32,768  (128 KB)
    //   qv:       B*D          =     8,192  (32 KB)
    float* partials = (float*)d_ws;
    float* avg = partials + (size_t)R_SLABS * BB * LC;
    float* qv  = avg + (size_t)BB * LC;

    kA_partials_qv<<<QV_BLOCKS + K1_BLOCKS, 256, 0, stream>>>(attn, q, partials, qv, out);
    k2_avg<<<(BB * LC) / 256, 256, 0, stream>>>(partials, avg);
    k4_finalize<<<BB, 256, 0, stream>>>(avg, qv, ctx, out);
}